// Round 12
// baseline (287.181 us; speedup 1.0000x reference)
//
#include <hip/hip_runtime.h>

// Match numpy f32 semantics: no FMA contraction anywhere in this TU.
#pragma clang fp contract(off)

#define VWD 96
#define NVERT 2048
#define NFAC 512
#define NBATCH 8
#define NSLAB 3456          // 12 x 12 x 24 slabs of 8x8x4 voxels
#define NWORK (NSLAB * NBATCH)
#define GRAIN 4             // slabs per atomic grab
#define RECF 16             // floats per facet body record (AoS, scalar-loaded)
#define CULC 22             // cull components (SoA): bbox 6 + 4 planes x 4

// SoA cull addressing: component c, batch b, facet f
#define CUL(c, b, f) cul[(size_t)(c) * (NBATCH * NFAC) + (size_t)(b) * NFAC + (f)]

// ---------------------------------------------------------------------------
// Kernel 1: per-batch facet precompute, ordered by |det| descending via a
// ONE-BARRIER rank sort. Fully scalarized. Body records SIGN-FOLDED: det<0 =>
// negate A,det (IEEE negation commutes exactly through mul/add/div, so
// n'/det' == n/det bit-for-bit). Also zeroes the work-steal counter.
//   body[b][s][16] : det, v3x,v3y,v3z, A00..A22, dhi, mhi, pad
//   dhi = det*(1-1e-5) - 1e-25   (definite-inside upper bound on sum)
//   mhi = det*(1+1e-5) + 1e-25   (maybe-inside upper bound; +-1e-25 guards
//                                 det=0 degenerate facets: ref l=NaN=outside)
// ---------------------------------------------------------------------------
__global__ __launch_bounds__(512) void precompute_kernel(
    const float* __restrict__ vertices,
    const int*   __restrict__ facets,
    float*       __restrict__ cul,
    float*       __restrict__ body,
    unsigned*    __restrict__ counter)
{
    __shared__ unsigned skey[NFAC];
    const int b = blockIdx.x;
    const int j = threadIdx.x;          // one facet per thread
    if (b == 0 && j == 0) *counter = 0u;   // work-steal queue head
    const float* vb = vertices + (size_t)b * NVERT * 3;

    int4 fi = ((const int4*)facets)[b * NFAC + j];
    float x0 = vb[3*fi.x+0], y0 = vb[3*fi.x+1], z0 = vb[3*fi.x+2];
    float x1 = vb[3*fi.y+0], y1 = vb[3*fi.y+1], z1 = vb[3*fi.y+2];
    float x2 = vb[3*fi.z+0], y2 = vb[3*fi.z+1], z2 = vb[3*fi.z+2];
    float x3 = vb[3*fi.w+0], y3 = vb[3*fi.w+1], z3 = vb[3*fi.w+2];
    float a  = x0-x3, bb = x1-x3, c  = x2-x3;
    float d  = y0-y3, e  = y1-y3, f  = y2-y3;
    float g  = z0-z3, h  = z1-z3, ii = z2-z3;
    float A00 = e*ii - f*h,  A01 = c*h  - bb*ii, A02 = bb*f - c*e;
    float A10 = f*g  - d*ii, A11 = a*ii - c*g,   A12 = c*d  - a*f;
    float A20 = d*h  - e*g,  A21 = bb*g - a*h,   A22 = a*e  - bb*d;
    float det = a*(e*ii - f*h) - bb*(d*ii - f*g) + c*(d*h - e*g);
    if (det < 0.0f) {   // sign-fold (exact)
        det = -det;
        A00 = -A00; A01 = -A01; A02 = -A02;
        A10 = -A10; A11 = -A11; A12 = -A12;
        A20 = -A20; A21 = -A21; A22 = -A22;
    }
    unsigned myk = ~__float_as_uint(det);   // ascending key == descending |det|
    skey[j] = myk;
    __syncthreads();

    // rank = #{k : key_k < myk or (key_k == myk and k < j)}  -> unique slot
    int rank = 0;
    const uint4* sk4 = (const uint4*)skey;
    for (int k0 = 0; k0 < NFAC; k0 += 4) {
        uint4 kk = sk4[k0 >> 2];
        rank += (kk.x < myk) + ((kk.x == myk) & (k0 + 0 < j));
        rank += (kk.y < myk) + ((kk.y == myk) & (k0 + 1 < j));
        rank += (kk.z < myk) + ((kk.z == myk) & (k0 + 2 < j));
        rank += (kk.w < myk) + ((kk.w == myk) & (k0 + 3 < j));
    }

    CUL(0, b, rank) = fminf(fminf(x0,x1),fminf(x2,x3)) - 1e-4f;
    CUL(1, b, rank) = fminf(fminf(y0,y1),fminf(y2,y3)) - 1e-4f;
    CUL(2, b, rank) = fminf(fminf(z0,z1),fminf(z2,z3)) - 1e-4f;
    CUL(3, b, rank) = fmaxf(fmaxf(x0,x1),fmaxf(x2,x3)) + 1e-4f;
    CUL(4, b, rank) = fmaxf(fmaxf(y0,y1),fmaxf(y2,y3)) + 1e-4f;
    CUL(5, b, rank) = fmaxf(fmaxf(z0,z1),fmaxf(z2,z3)) + 1e-4f;

    // 4 outward face planes, margin-inflated, slab half-extents folded:
    // mask test becomes  dot(n, slab_center) <= rhs  (conservative).
    const float HX = 7.0f/96.0f, HZ = 3.0f/96.0f;
    auto plane = [&](float pax, float pay, float paz,
                     float pbx, float pby, float pbz,
                     float pcx, float pcy, float pcz,
                     float pox, float poy, float poz, int base) {
        float e1x = pbx-pax, e1y = pby-pay, e1z = pbz-paz;
        float e2x = pcx-pax, e2y = pcy-pay, e2z = pcz-paz;
        float nx = e1y*e2z - e1z*e2y;
        float ny = e1z*e2x - e1x*e2z;
        float nz = e1x*e2y - e1y*e2x;
        float sdot = nx*(pox-pax) + ny*(poy-pay) + nz*(poz-paz);
        if (sdot > 0.0f) { nx=-nx; ny=-ny; nz=-nz; sdot=-sdot; }
        float dpl = nx*pax + ny*pay + nz*paz;
        float n1s = fabsf(nx)+fabsf(ny)+fabsf(nz);
        float M = 1e-4f*(-sdot) + 1e-4f*n1s + 1e-4f;
        float rhs = dpl + M + (fabsf(nx)*HX + fabsf(ny)*HX + fabsf(nz)*HZ);
        CUL(base+0, b, rank) = nx;
        CUL(base+1, b, rank) = ny;
        CUL(base+2, b, rank) = nz;
        CUL(base+3, b, rank) = rhs;
    };
    plane(x1,y1,z1, x2,y2,z2, x3,y3,z3, x0,y0,z0, 6);    // opposite v0
    plane(x0,y0,z0, x2,y2,z2, x3,y3,z3, x1,y1,z1, 10);   // opposite v1
    plane(x0,y0,z0, x1,y1,z1, x3,y3,z3, x2,y2,z2, 14);   // opposite v2
    plane(x0,y0,z0, x1,y1,z1, x2,y2,z2, x3,y3,z3, 18);   // opposite v3

    float* bo = body + ((size_t)b * NFAC + rank) * RECF;
    bo[0]  = det; bo[1]  = x3;  bo[2]  = y3;  bo[3]  = z3;
    bo[4]  = A00; bo[5]  = A01; bo[6]  = A02;
    bo[7]  = A10; bo[8]  = A11; bo[9]  = A12;
    bo[10] = A20; bo[11] = A21; bo[12] = A22;
    bo[13] = det * (1.0f - 1e-5f) - 1e-25f;   // dhi
    bo[14] = det * (1.0f + 1e-5f) + 1e-25f;   // mhi
    bo[15] = 0.0f;
}

// ---------------------------------------------------------------------------
// Kernel 2: per-slab 512-bit facet mask. One block per (batch, x-y column);
// facet-per-lane, cull record loaded ONCE (SoA, coalesced), 24 z-slabs via
// incremental plane dots (error ~3e-6 << 1e-4 margin folded into rhs).
// ---------------------------------------------------------------------------
__global__ __launch_bounds__(512) void mask_kernel(
    const float* __restrict__ cul,
    unsigned long long* __restrict__ masks)
{
    const int col = blockIdx.x;           // 0..143 = sx*12+sy
    const int b   = blockIdx.y;
    const int f   = threadIdx.x;          // facet (sorted order)
    const int w   = threadIdx.x >> 6;
    float bminx=CUL(0,b,f), bminy=CUL(1,b,f), bminz=CUL(2,b,f);
    float bmaxx=CUL(3,b,f), bmaxy=CUL(4,b,f), bmaxz=CUL(5,b,f);
    float n0x=CUL(6,b,f),  n0y=CUL(7,b,f),  n0z=CUL(8,b,f),  r0=CUL(9,b,f);
    float n1x=CUL(10,b,f), n1y=CUL(11,b,f), n1z=CUL(12,b,f), r1=CUL(13,b,f);
    float n2x=CUL(14,b,f), n2y=CUL(15,b,f), n2z=CUL(16,b,f), r2=CUL(17,b,f);
    float n3x=CUL(18,b,f), n3y=CUL(19,b,f), n3z=CUL(20,b,f), r3=CUL(21,b,f);

    const int sx = col / 12, sy = col % 12;
    const float cx = (float)(16*sx + 8 - VWD) / 96.0f;
    const float cy = (float)(16*sy + 8 - VWD) / 96.0f;
    const float colminx = (float)(16*sx + 1  - VWD) / 96.0f;
    const float colmaxx = (float)(16*sx + 15 - VWD) / 96.0f;
    const float colminy = (float)(16*sy + 1  - VWD) / 96.0f;
    const float colmaxy = (float)(16*sy + 15 - VWD) / 96.0f;
    const bool ovxy = (bminx <= colmaxx) & (bmaxx >= colminx) &
                      (bminy <= colmaxy) & (bmaxy >= colminy);

    const float cz0   = (float)(4 - VWD) / 96.0f;   // z-center of slab sz=0
    const float stepc = 8.0f / 96.0f;
    float d0 = n0x*cx + n0y*cy + n0z*cz0 - r0;  float s0 = n0z*stepc;
    float d1 = n1x*cx + n1y*cy + n1z*cz0 - r1;  float s1 = n1z*stepc;
    float d2 = n2x*cx + n2y*cy + n2z*cz0 - r2;  float s2 = n2z*stepc;
    float d3 = n3x*cx + n3y*cy + n3z*cz0 - r3;  float s3 = n3z*stepc;
    float zlo = (float)(1 - VWD) / 96.0f;
    float zhi = (float)(7 - VWD) / 96.0f;

    unsigned long long* mp = masks + ((size_t)b * NSLAB + (size_t)col * 24) * 8 + w;
#pragma unroll 4
    for (int sz = 0; sz < 24; ++sz) {
        bool ov = ovxy & (bminz <= zhi) & (bmaxz >= zlo) &
                  (d0 <= 0.0f) & (d1 <= 0.0f) & (d2 <= 0.0f) & (d3 <= 0.0f);
        unsigned long long bal = __ballot((int)ov);
        if ((threadIdx.x & 63) == 0) mp[(size_t)sz * 8] = bal;
        d0 += s0; d1 += s1; d2 += s2; d3 += s3;
        zlo += stepc; zhi += stepc;
    }
}

// ---------------------------------------------------------------------------
// Kernel 3: PERSISTENT-WAVE work stealing. 2048 blocks (8/CU resident for the
// whole kernel, 32 waves/CU) each grab GRAIN slabs per atomicAdd until the
// 27648-item queue drains — structural latency hiding + no early-exit tail.
// Per-slab math identical to R11 (bit-exact numerators; exact l_i>=0 test;
// det-relative shell on the sum; exact ref path only in the shell).
// ---------------------------------------------------------------------------
__global__ __launch_bounds__(256) void voxelize_kernel(
    const float*              __restrict__ body,
    const unsigned long long* __restrict__ masks,
    float*                    __restrict__ out,
    unsigned*                 __restrict__ counter)
{
    const int lane = threadIdx.x & 63;

    for (;;) {
        unsigned g;
        if (lane == 0) g = atomicAdd(counter, 1u);
        g = (unsigned)__builtin_amdgcn_readfirstlane((int)g);
        if (g >= NWORK / GRAIN) return;

        for (int t = 0; t < GRAIN; ++t) {
            const unsigned id = g * GRAIN + t;
            const int b    = id / NSLAB;
            const int slab = id % NSLAB;
            const int sz = slab % 24;
            const int sy = (slab / 24) % 12;
            const int sx = slab / 288;
            const int ix  = sx*8 + (lane >> 3);
            const int iy  = sy*8 + (lane & 7);
            const int iz0 = sz*4;

            const float px  = (float)(2*ix + 1 - VWD) / 96.0f;
            const float py  = (float)(2*iy + 1 - VWD) / 96.0f;
            const float pz0 = (float)(2*(iz0+0) + 1 - VWD) / 96.0f;
            const float pz1 = (float)(2*(iz0+1) + 1 - VWD) / 96.0f;
            const float pz2 = (float)(2*(iz0+2) + 1 - VWD) / 96.0f;
            const float pz3 = (float)(2*(iz0+3) + 1 - VWD) / 96.0f;

            const unsigned long long* mp = masks + ((size_t)b * NSLAB + slab) * 8;
            const float* bb = body + (size_t)b * NFAC * RECF;

            unsigned fnd = 0u;   // bit k = voxel (ix,iy,iz0+k) found
            for (int w = 0; w < 8; ++w) {
                unsigned long long m = mp[w];   // wave-uniform -> SGPR
                while (m) {
                    int bit = __builtin_ctzll(m);
                    m &= m - 1;
                    int f = __builtin_amdgcn_readfirstlane(w * 64 + bit);
                    const float* bo = bb + f * RECF;
                    float det = bo[0], v3x = bo[1], v3y = bo[2], v3z = bo[3];
                    float A00 = bo[4],  A01 = bo[5],  A02 = bo[6];
                    float A10 = bo[7],  A11 = bo[8],  A12 = bo[9];
                    float A20 = bo[10], A21 = bo[11], A22 = bo[12];
                    float dhi = bo[13], mhi = bo[14];
                    float dx = px - v3x, dy = py - v3y;
                    // ref-exact partials (left-assoc, contract off)
                    float p0 = A00*dx + A01*dy;
                    float p1 = A10*dx + A11*dy;
                    float p2 = A20*dx + A21*dy;
                    float dzk0 = pz0 - v3z, dzk1 = pz1 - v3z;
                    float dzk2 = pz2 - v3z, dzk3 = pz3 - v3z;
#pragma unroll
                    for (int k = 0; k < 4; ++k) {
                        float dzk = (k == 0) ? dzk0 : (k == 1) ? dzk1
                                  : (k == 2) ? dzk2 : dzk3;
                        // n_i bit-identical to reference's numerators
                        float n0 = p0 + A02*dzk;
                        float n1 = p1 + A12*dzk;
                        float n2 = p2 + A22*dzk;
                        float sm = (n0 + n1) + n2;
                        float mn = fminf(fminf(n0, n1), n2);   // v_min3_f32
                        bool ge0 = (mn >= 0.0f);               // EXACT l_i>=0
                        bool def = ge0 & (sm <= dhi);
                        bool may = ge0 & (sm <= mhi);
                        bool needex = may & !def & !((fnd >> k) & 1u);
                        if (__any(needex)) {
                            // exact path (rare): ref's divisions + final test
                            float l0 = n0 / det;
                            float l1 = n1 / det;
                            float l2 = n2 / det;
                            float l3 = 1.0f - ((l0 + l1) + l2);
                            bool inside = (l0 >= 0.0f) & (l0 <= 1.0f) &
                                          (l1 >= 0.0f) & (l1 <= 1.0f) &
                                          (l2 >= 0.0f) & (l2 <= 1.0f) &
                                          (l3 >= 0.0f) & (l3 <= 1.0f);
                            if (needex & inside) fnd |= (1u << k);
                        }
                        if (def) fnd |= (1u << k);
                    }
                    if (__all(fnd == 15u)) goto slab_done;
                }
            }
slab_done:
            {
                float4 v;
                v.x = (fnd & 1u) ? 1.0f : 0.0f;
                v.y = (fnd & 2u) ? 1.0f : 0.0f;
                v.z = (fnd & 4u) ? 1.0f : 0.0f;
                v.w = (fnd & 8u) ? 1.0f : 0.0f;
                *(float4*)&out[(size_t)b*(VWD*VWD*VWD)
                               + (size_t)ix*(VWD*VWD) + iy*VWD + iz0] = v;
            }
        }
    }
}

extern "C" void kernel_launch(void* const* d_in, const int* in_sizes, int n_in,
                              void* d_out, int out_size, void* d_ws, size_t ws_size,
                              hipStream_t stream) {
    const float* vertices = (const float*)d_in[0];   // (8, 2048, 3) f32
    const int*   facets   = (const int*)d_in[1];     // (8, 512, 4) int
    float*       out      = (float*)d_out;           // (8, 96, 96, 96) f32

    // d_ws layout: cul SoA (352 KB) | body (256 KB) | masks (1.73 MB) | counter
    float* cul  = (float*)d_ws;
    float* body = (float*)((char*)d_ws + (size_t)CULC * NBATCH * NFAC * 4);
    char*  after_body = (char*)d_ws + (size_t)(CULC + RECF) * NBATCH * NFAC * 4;
    unsigned long long* msk = (unsigned long long*)after_body;
    unsigned* counter =
        (unsigned*)(after_body + (size_t)NBATCH * NSLAB * 8 * sizeof(unsigned long long));

    precompute_kernel<<<NBATCH, 512, 0, stream>>>(vertices, facets, cul, body, counter);
    mask_kernel<<<dim3(144, NBATCH), 512, 0, stream>>>(cul, msk);
    voxelize_kernel<<<2048, 256, 0, stream>>>(body, msk, out, counter);
}

// Round 13
// 150.396 us; speedup vs baseline: 1.9095x; 1.9095x over previous
//
#include <hip/hip_runtime.h>

// Match numpy f32 semantics: no FMA contraction anywhere in this TU.
#pragma clang fp contract(off)

#define VWD 96
#define NVERT 2048
#define NFAC 512
#define NBATCH 8
#define NSLAB 3456          // 12 x 12 x 24 slabs of 8x8x4 voxels
#define RECF 16             // floats per facet body record
#define CULC 22             // cull components (SoA): bbox 6 + 4 planes x 4

// SoA cull addressing: component c, batch b, facet f
#define CUL(c, b, f) cul[(size_t)(c) * (NBATCH * NFAC) + (size_t)(b) * NFAC + (f)]

// ---------------------------------------------------------------------------
// Kernel 1: per-batch facet precompute, ordered by |det| descending via a
// ONE-BARRIER rank sort. Fully scalarized. Body records SIGN-FOLDED: det<0 =>
// negate A,det (IEEE negation commutes exactly through mul/add/div, so
// n'/det' == n/det bit-for-bit).
//   body[b][s][16] : det,v3x,v3y,v3z, A00,A01,A02,A10, A11,A12,A20,A21,
//                    A22, dhi, mhi, pad   (float4-aligned quads)
//   dhi = det*(1-1e-5) - 1e-25   (definite-inside upper bound on sum)
//   mhi = det*(1+1e-5) + 1e-25   (maybe-inside upper bound; +-1e-25 guards
//                                 det=0 degenerate facets: ref l=NaN=outside)
// ---------------------------------------------------------------------------
__global__ __launch_bounds__(512) void precompute_kernel(
    const float* __restrict__ vertices,
    const int*   __restrict__ facets,
    float*       __restrict__ cul,
    float*       __restrict__ body)
{
    __shared__ unsigned skey[NFAC];
    const int b = blockIdx.x;
    const int j = threadIdx.x;          // one facet per thread
    const float* vb = vertices + (size_t)b * NVERT * 3;

    int4 fi = ((const int4*)facets)[b * NFAC + j];
    float x0 = vb[3*fi.x+0], y0 = vb[3*fi.x+1], z0 = vb[3*fi.x+2];
    float x1 = vb[3*fi.y+0], y1 = vb[3*fi.y+1], z1 = vb[3*fi.y+2];
    float x2 = vb[3*fi.z+0], y2 = vb[3*fi.z+1], z2 = vb[3*fi.z+2];
    float x3 = vb[3*fi.w+0], y3 = vb[3*fi.w+1], z3 = vb[3*fi.w+2];
    float a  = x0-x3, bb = x1-x3, c  = x2-x3;
    float d  = y0-y3, e  = y1-y3, f  = y2-y3;
    float g  = z0-z3, h  = z1-z3, ii = z2-z3;
    float A00 = e*ii - f*h,  A01 = c*h  - bb*ii, A02 = bb*f - c*e;
    float A10 = f*g  - d*ii, A11 = a*ii - c*g,   A12 = c*d  - a*f;
    float A20 = d*h  - e*g,  A21 = bb*g - a*h,   A22 = a*e  - bb*d;
    float det = a*(e*ii - f*h) - bb*(d*ii - f*g) + c*(d*h - e*g);
    if (det < 0.0f) {   // sign-fold (exact)
        det = -det;
        A00 = -A00; A01 = -A01; A02 = -A02;
        A10 = -A10; A11 = -A11; A12 = -A12;
        A20 = -A20; A21 = -A21; A22 = -A22;
    }
    unsigned myk = ~__float_as_uint(det);   // ascending key == descending |det|
    skey[j] = myk;
    __syncthreads();

    // rank = #{k : key_k < myk or (key_k == myk and k < j)}  -> unique slot
    int rank = 0;
    const uint4* sk4 = (const uint4*)skey;
    for (int k0 = 0; k0 < NFAC; k0 += 4) {
        uint4 kk = sk4[k0 >> 2];
        rank += (kk.x < myk) + ((kk.x == myk) & (k0 + 0 < j));
        rank += (kk.y < myk) + ((kk.y == myk) & (k0 + 1 < j));
        rank += (kk.z < myk) + ((kk.z == myk) & (k0 + 2 < j));
        rank += (kk.w < myk) + ((kk.w == myk) & (k0 + 3 < j));
    }

    CUL(0, b, rank) = fminf(fminf(x0,x1),fminf(x2,x3)) - 1e-4f;
    CUL(1, b, rank) = fminf(fminf(y0,y1),fminf(y2,y3)) - 1e-4f;
    CUL(2, b, rank) = fminf(fminf(z0,z1),fminf(z2,z3)) - 1e-4f;
    CUL(3, b, rank) = fmaxf(fmaxf(x0,x1),fmaxf(x2,x3)) + 1e-4f;
    CUL(4, b, rank) = fmaxf(fmaxf(y0,y1),fmaxf(y2,y3)) + 1e-4f;
    CUL(5, b, rank) = fmaxf(fmaxf(z0,z1),fmaxf(z2,z3)) + 1e-4f;

    // 4 outward face planes, margin-inflated, slab half-extents folded:
    // mask test becomes  dot(n, slab_center) <= rhs  (conservative).
    const float HX = 7.0f/96.0f, HZ = 3.0f/96.0f;
    auto plane = [&](float pax, float pay, float paz,
                     float pbx, float pby, float pbz,
                     float pcx, float pcy, float pcz,
                     float pox, float poy, float poz, int base) {
        float e1x = pbx-pax, e1y = pby-pay, e1z = pbz-paz;
        float e2x = pcx-pax, e2y = pcy-pay, e2z = pcz-paz;
        float nx = e1y*e2z - e1z*e2y;
        float ny = e1z*e2x - e1x*e2z;
        float nz = e1x*e2y - e1y*e2x;
        float sdot = nx*(pox-pax) + ny*(poy-pay) + nz*(poz-paz);
        if (sdot > 0.0f) { nx=-nx; ny=-ny; nz=-nz; sdot=-sdot; }
        float dpl = nx*pax + ny*pay + nz*paz;
        float n1s = fabsf(nx)+fabsf(ny)+fabsf(nz);
        float M = 1e-4f*(-sdot) + 1e-4f*n1s + 1e-4f;
        float rhs = dpl + M + (fabsf(nx)*HX + fabsf(ny)*HX + fabsf(nz)*HZ);
        CUL(base+0, b, rank) = nx;
        CUL(base+1, b, rank) = ny;
        CUL(base+2, b, rank) = nz;
        CUL(base+3, b, rank) = rhs;
    };
    plane(x1,y1,z1, x2,y2,z2, x3,y3,z3, x0,y0,z0, 6);    // opposite v0
    plane(x0,y0,z0, x2,y2,z2, x3,y3,z3, x1,y1,z1, 10);   // opposite v1
    plane(x0,y0,z0, x1,y1,z1, x3,y3,z3, x2,y2,z2, 14);   // opposite v2
    plane(x0,y0,z0, x1,y1,z1, x2,y2,z2, x3,y3,z3, 18);   // opposite v3

    float* bo = body + ((size_t)b * NFAC + rank) * RECF;
    bo[0]  = det; bo[1]  = x3;  bo[2]  = y3;  bo[3]  = z3;
    bo[4]  = A00; bo[5]  = A01; bo[6]  = A02; bo[7]  = A10;
    bo[8]  = A11; bo[9]  = A12; bo[10] = A20; bo[11] = A21;
    bo[12] = A22;
    bo[13] = det * (1.0f - 1e-5f) - 1e-25f;   // dhi
    bo[14] = det * (1.0f + 1e-5f) + 1e-25f;   // mhi
    bo[15] = 0.0f;
}

// ---------------------------------------------------------------------------
// Kernel 2: per-slab 512-bit facet mask. One block per (batch, x-y column);
// facet-per-lane, cull record loaded ONCE (SoA, coalesced), 24 z-slabs via
// incremental plane dots (error ~3e-6 << 1e-4 margin folded into rhs).
// ---------------------------------------------------------------------------
__global__ __launch_bounds__(512) void mask_kernel(
    const float* __restrict__ cul,
    unsigned long long* __restrict__ masks)
{
    const int col = blockIdx.x;           // 0..143 = sx*12+sy
    const int b   = blockIdx.y;
    const int f   = threadIdx.x;          // facet (sorted order)
    const int w   = threadIdx.x >> 6;
    float bminx=CUL(0,b,f), bminy=CUL(1,b,f), bminz=CUL(2,b,f);
    float bmaxx=CUL(3,b,f), bmaxy=CUL(4,b,f), bmaxz=CUL(5,b,f);
    float n0x=CUL(6,b,f),  n0y=CUL(7,b,f),  n0z=CUL(8,b,f),  r0=CUL(9,b,f);
    float n1x=CUL(10,b,f), n1y=CUL(11,b,f), n1z=CUL(12,b,f), r1=CUL(13,b,f);
    float n2x=CUL(14,b,f), n2y=CUL(15,b,f), n2z=CUL(16,b,f), r2=CUL(17,b,f);
    float n3x=CUL(18,b,f), n3y=CUL(19,b,f), n3z=CUL(20,b,f), r3=CUL(21,b,f);

    const int sx = col / 12, sy = col % 12;
    const float cx = (float)(16*sx + 8 - VWD) / 96.0f;
    const float cy = (float)(16*sy + 8 - VWD) / 96.0f;
    const float colminx = (float)(16*sx + 1  - VWD) / 96.0f;
    const float colmaxx = (float)(16*sx + 15 - VWD) / 96.0f;
    const float colminy = (float)(16*sy + 1  - VWD) / 96.0f;
    const float colmaxy = (float)(16*sy + 15 - VWD) / 96.0f;
    const bool ovxy = (bminx <= colmaxx) & (bmaxx >= colminx) &
                      (bminy <= colmaxy) & (bmaxy >= colminy);

    const float cz0   = (float)(4 - VWD) / 96.0f;   // z-center of slab sz=0
    const float stepc = 8.0f / 96.0f;
    float d0 = n0x*cx + n0y*cy + n0z*cz0 - r0;  float s0 = n0z*stepc;
    float d1 = n1x*cx + n1y*cy + n1z*cz0 - r1;  float s1 = n1z*stepc;
    float d2 = n2x*cx + n2y*cy + n2z*cz0 - r2;  float s2 = n2z*stepc;
    float d3 = n3x*cx + n3y*cy + n3z*cz0 - r3;  float s3 = n3z*stepc;
    float zlo = (float)(1 - VWD) / 96.0f;
    float zhi = (float)(7 - VWD) / 96.0f;

    unsigned long long* mp = masks + ((size_t)b * NSLAB + (size_t)col * 24) * 8 + w;
#pragma unroll 4
    for (int sz = 0; sz < 24; ++sz) {
        bool ov = ovxy & (bminz <= zhi) & (bmaxz >= zlo) &
                  (d0 <= 0.0f) & (d1 <= 0.0f) & (d2 <= 0.0f) & (d3 <= 0.0f);
        unsigned long long bal = __ballot((int)ov);
        if ((threadIdx.x & 63) == 0) mp[(size_t)sz * 8] = bal;
        d0 += s0; d1 += s1; d2 += s2; d3 += s3;
        zlo += stepc; zhi += stepc;
    }
}

// ---------------------------------------------------------------------------
// Kernel 3 (R11 math, VECTOR-BROADCAST record loads): one wave per 8x8x4 slab
// (4 z-voxels/lane). The facet index is forced into a VGPR so the 64-B record
// is fetched with global_load_dwordx4 (all lanes same address -> one request
// + broadcast) through the per-CU 32-KB vL1, which holds the whole 32-KB
// batch body table -> ~30-cyc hits instead of ~200-cyc scalar-cache misses.
// Numerators bit-identical to ref; exact l_i>=0 sign test; det-relative shell
// on the sum; exact ref path (divisions) only inside the shell.
// ---------------------------------------------------------------------------
__global__ __launch_bounds__(256) void voxelize_kernel(
    const float*              __restrict__ body,
    const unsigned long long* __restrict__ masks,
    float*                    __restrict__ out)
{
    const int b    = blockIdx.y;
    const int wave = threadIdx.x >> 6;
    const int lane = threadIdx.x & 63;
    const int slab = blockIdx.x * 4 + wave;          // 0 .. 3455
    const int sz = slab % 24;
    const int sy = (slab / 24) % 12;
    const int sx = slab / 288;
    const int ix  = sx*8 + (lane >> 3);
    const int iy  = sy*8 + (lane & 7);
    const int iz0 = sz*4;

    const float px  = (float)(2*ix + 1 - VWD) / 96.0f;
    const float py  = (float)(2*iy + 1 - VWD) / 96.0f;
    const float pz0 = (float)(2*(iz0+0) + 1 - VWD) / 96.0f;
    const float pz1 = (float)(2*(iz0+1) + 1 - VWD) / 96.0f;
    const float pz2 = (float)(2*(iz0+2) + 1 - VWD) / 96.0f;
    const float pz3 = (float)(2*(iz0+3) + 1 - VWD) / 96.0f;

    const unsigned long long* mp = masks + ((size_t)b * NSLAB + slab) * 8;
    const float4* bbv = (const float4*)(body + (size_t)b * NFAC * RECF);

    unsigned fnd = 0u;   // bit k = voxel (ix,iy,iz0+k) found
    for (int w = 0; w < 8; ++w) {
        unsigned long long m = mp[w];   // wave-uniform -> SGPR
        while (m) {
            int bit = __builtin_ctzll(m);
            m &= m - 1;
            int f = w * 64 + bit;
            // force index into a VGPR -> vector loads (vL1 broadcast path)
            int fv;
            asm("v_mov_b32 %0, %1" : "=v"(fv) : "r"(f));
            float4 c0 = bbv[fv*4+0];   // det, v3x, v3y, v3z
            float4 c1 = bbv[fv*4+1];   // A00, A01, A02, A10
            float4 c2 = bbv[fv*4+2];   // A11, A12, A20, A21
            float4 c3 = bbv[fv*4+3];   // A22, dhi, mhi, pad
            float det = c0.x, v3x = c0.y, v3y = c0.z, v3z = c0.w;
            float A00 = c1.x, A01 = c1.y, A02 = c1.z, A10 = c1.w;
            float A11 = c2.x, A12 = c2.y, A20 = c2.z, A21 = c2.w;
            float A22 = c3.x, dhi = c3.y, mhi = c3.z;
            float dx = px - v3x, dy = py - v3y;
            // ref-exact partials (left-assoc, contract off)
            float p0 = A00*dx + A01*dy;
            float p1 = A10*dx + A11*dy;
            float p2 = A20*dx + A21*dy;
            float dzk0 = pz0 - v3z, dzk1 = pz1 - v3z;
            float dzk2 = pz2 - v3z, dzk3 = pz3 - v3z;
#pragma unroll
            for (int k = 0; k < 4; ++k) {
                float dzk = (k == 0) ? dzk0 : (k == 1) ? dzk1
                          : (k == 2) ? dzk2 : dzk3;
                // n_i bit-identical to reference's numerators
                float n0 = p0 + A02*dzk;
                float n1 = p1 + A12*dzk;
                float n2 = p2 + A22*dzk;
                float sm = (n0 + n1) + n2;
                float mn = fminf(fminf(n0, n1), n2);   // v_min3_f32
                bool ge0 = (mn >= 0.0f);               // EXACT l_i>=0 test
                bool def = ge0 & (sm <= dhi);
                bool may = ge0 & (sm <= mhi);
                bool needex = may & !def & !((fnd >> k) & 1u);
                if (__any(needex)) {
                    // exact path (rare): ref's divisions + final test
                    float l0 = n0 / det;
                    float l1 = n1 / det;
                    float l2 = n2 / det;
                    float l3 = 1.0f - ((l0 + l1) + l2);
                    bool inside = (l0 >= 0.0f) & (l0 <= 1.0f) &
                                  (l1 >= 0.0f) & (l1 <= 1.0f) &
                                  (l2 >= 0.0f) & (l2 <= 1.0f) &
                                  (l3 >= 0.0f) & (l3 <= 1.0f);
                    if (needex & inside) fnd |= (1u << k);
                }
                if (def) fnd |= (1u << k);
            }
            if (__all(fnd == 15u)) goto done;
        }
    }
done:
    float4 v;
    v.x = (fnd & 1u) ? 1.0f : 0.0f;
    v.y = (fnd & 2u) ? 1.0f : 0.0f;
    v.z = (fnd & 4u) ? 1.0f : 0.0f;
    v.w = (fnd & 8u) ? 1.0f : 0.0f;
    *(float4*)&out[(size_t)b*(VWD*VWD*VWD) + (size_t)ix*(VWD*VWD) + iy*VWD + iz0] = v;
}

extern "C" void kernel_launch(void* const* d_in, const int* in_sizes, int n_in,
                              void* d_out, int out_size, void* d_ws, size_t ws_size,
                              hipStream_t stream) {
    const float* vertices = (const float*)d_in[0];   // (8, 2048, 3) f32
    const int*   facets   = (const int*)d_in[1];     // (8, 512, 4) int
    float*       out      = (float*)d_out;           // (8, 96, 96, 96) f32

    // d_ws layout: cul SoA (352 KB) | body (256 KB) | masks (1.73 MB)
    float* cul  = (float*)d_ws;
    float* body = (float*)((char*)d_ws + (size_t)CULC * NBATCH * NFAC * 4);
    unsigned long long* msk =
        (unsigned long long*)((char*)d_ws +
                              (size_t)(CULC + RECF) * NBATCH * NFAC * 4);

    precompute_kernel<<<NBATCH, 512, 0, stream>>>(vertices, facets, cul, body);
    mask_kernel<<<dim3(144, NBATCH), 512, 0, stream>>>(cul, msk);
    dim3 grid(NSLAB / 4, NBATCH);   // 864 blocks * 4 waves = 3456 slabs/batch
    voxelize_kernel<<<grid, 256, 0, stream>>>(body, msk, out);
}

// Round 14
// 144.367 us; speedup vs baseline: 1.9892x; 1.0418x over previous
//
#include <hip/hip_runtime.h>

// Match numpy f32 semantics: no FMA contraction anywhere in this TU.
#pragma clang fp contract(off)

#define VWD 96
#define NVERT 2048
#define NFAC 512
#define NBATCH 8
#define NSLAB 3456          // 12 x 12 x 24 slabs of 8x8x4 voxels
#define RECF 16             // floats per facet body record
#define CULC 22             // cull components (SoA): bbox 6 + 4 planes x 4

// SoA cull addressing: component c, batch b, facet f
#define CUL(c, b, f) cul[(size_t)(c) * (NBATCH * NFAC) + (size_t)(b) * NFAC + (f)]

// ---------------------------------------------------------------------------
// Kernel 1: per-batch facet precompute, ordered by |det| descending via a
// ONE-BARRIER rank sort. Fully scalarized. Body records SIGN-FOLDED: det<0 =>
// negate A,det (IEEE negation commutes exactly through mul/add/div, so
// n'/det' == n/det bit-for-bit).
//   body[b][s][16] : det,v3x,v3y,v3z, A00..A22, dhi, mhi, pad
//   dhi = det*(1-1e-5) - 1e-25   (definite-inside upper bound on sum)
//   mhi = det*(1+1e-5) + 1e-25   (maybe-inside upper bound; +-1e-25 guards
//                                 det=0 degenerate facets: ref l=NaN=outside)
// ---------------------------------------------------------------------------
__global__ __launch_bounds__(512) void precompute_kernel(
    const float* __restrict__ vertices,
    const int*   __restrict__ facets,
    float*       __restrict__ cul,
    float*       __restrict__ body)
{
    __shared__ unsigned skey[NFAC];
    const int b = blockIdx.x;
    const int j = threadIdx.x;          // one facet per thread
    const float* vb = vertices + (size_t)b * NVERT * 3;

    int4 fi = ((const int4*)facets)[b * NFAC + j];
    float x0 = vb[3*fi.x+0], y0 = vb[3*fi.x+1], z0 = vb[3*fi.x+2];
    float x1 = vb[3*fi.y+0], y1 = vb[3*fi.y+1], z1 = vb[3*fi.y+2];
    float x2 = vb[3*fi.z+0], y2 = vb[3*fi.z+1], z2 = vb[3*fi.z+2];
    float x3 = vb[3*fi.w+0], y3 = vb[3*fi.w+1], z3 = vb[3*fi.w+2];
    float a  = x0-x3, bb = x1-x3, c  = x2-x3;
    float d  = y0-y3, e  = y1-y3, f  = y2-y3;
    float g  = z0-z3, h  = z1-z3, ii = z2-z3;
    float A00 = e*ii - f*h,  A01 = c*h  - bb*ii, A02 = bb*f - c*e;
    float A10 = f*g  - d*ii, A11 = a*ii - c*g,   A12 = c*d  - a*f;
    float A20 = d*h  - e*g,  A21 = bb*g - a*h,   A22 = a*e  - bb*d;
    float det = a*(e*ii - f*h) - bb*(d*ii - f*g) + c*(d*h - e*g);
    if (det < 0.0f) {   // sign-fold (exact)
        det = -det;
        A00 = -A00; A01 = -A01; A02 = -A02;
        A10 = -A10; A11 = -A11; A12 = -A12;
        A20 = -A20; A21 = -A21; A22 = -A22;
    }
    unsigned myk = ~__float_as_uint(det);   // ascending key == descending |det|
    skey[j] = myk;
    __syncthreads();

    // rank = #{k : key_k < myk or (key_k == myk and k < j)}  -> unique slot
    int rank = 0;
    const uint4* sk4 = (const uint4*)skey;
    for (int k0 = 0; k0 < NFAC; k0 += 4) {
        uint4 kk = sk4[k0 >> 2];
        rank += (kk.x < myk) + ((kk.x == myk) & (k0 + 0 < j));
        rank += (kk.y < myk) + ((kk.y == myk) & (k0 + 1 < j));
        rank += (kk.z < myk) + ((kk.z == myk) & (k0 + 2 < j));
        rank += (kk.w < myk) + ((kk.w == myk) & (k0 + 3 < j));
    }

    CUL(0, b, rank) = fminf(fminf(x0,x1),fminf(x2,x3)) - 1e-4f;
    CUL(1, b, rank) = fminf(fminf(y0,y1),fminf(y2,y3)) - 1e-4f;
    CUL(2, b, rank) = fminf(fminf(z0,z1),fminf(z2,z3)) - 1e-4f;
    CUL(3, b, rank) = fmaxf(fmaxf(x0,x1),fmaxf(x2,x3)) + 1e-4f;
    CUL(4, b, rank) = fmaxf(fmaxf(y0,y1),fmaxf(y2,y3)) + 1e-4f;
    CUL(5, b, rank) = fmaxf(fmaxf(z0,z1),fmaxf(z2,z3)) + 1e-4f;

    // 4 outward face planes, margin-inflated, slab half-extents folded:
    // mask test becomes  dot(n, slab_center) <= rhs  (conservative).
    const float HX = 7.0f/96.0f, HZ = 3.0f/96.0f;
    auto plane = [&](float pax, float pay, float paz,
                     float pbx, float pby, float pbz,
                     float pcx, float pcy, float pcz,
                     float pox, float poy, float poz, int base) {
        float e1x = pbx-pax, e1y = pby-pay, e1z = pbz-paz;
        float e2x = pcx-pax, e2y = pcy-pay, e2z = pcz-paz;
        float nx = e1y*e2z - e1z*e2y;
        float ny = e1z*e2x - e1x*e2z;
        float nz = e1x*e2y - e1y*e2x;
        float sdot = nx*(pox-pax) + ny*(poy-pay) + nz*(poz-paz);
        if (sdot > 0.0f) { nx=-nx; ny=-ny; nz=-nz; sdot=-sdot; }
        float dpl = nx*pax + ny*pay + nz*paz;
        float n1s = fabsf(nx)+fabsf(ny)+fabsf(nz);
        float M = 1e-4f*(-sdot) + 1e-4f*n1s + 1e-4f;
        float rhs = dpl + M + (fabsf(nx)*HX + fabsf(ny)*HX + fabsf(nz)*HZ);
        CUL(base+0, b, rank) = nx;
        CUL(base+1, b, rank) = ny;
        CUL(base+2, b, rank) = nz;
        CUL(base+3, b, rank) = rhs;
    };
    plane(x1,y1,z1, x2,y2,z2, x3,y3,z3, x0,y0,z0, 6);    // opposite v0
    plane(x0,y0,z0, x2,y2,z2, x3,y3,z3, x1,y1,z1, 10);   // opposite v1
    plane(x0,y0,z0, x1,y1,z1, x3,y3,z3, x2,y2,z2, 14);   // opposite v2
    plane(x0,y0,z0, x1,y1,z1, x2,y2,z2, x3,y3,z3, 18);   // opposite v3

    float* bo = body + ((size_t)b * NFAC + rank) * RECF;
    bo[0]  = det; bo[1]  = x3;  bo[2]  = y3;  bo[3]  = z3;
    bo[4]  = A00; bo[5]  = A01; bo[6]  = A02; bo[7]  = A10;
    bo[8]  = A11; bo[9]  = A12; bo[10] = A20; bo[11] = A21;
    bo[12] = A22;
    bo[13] = det * (1.0f - 1e-5f) - 1e-25f;   // dhi
    bo[14] = det * (1.0f + 1e-5f) + 1e-25f;   // mhi
    bo[15] = 0.0f;
}

// ---------------------------------------------------------------------------
// Kernel 2: per-slab 512-bit facet mask. One block per (batch, x-y column);
// facet-per-lane, cull record loaded ONCE (SoA, coalesced), 24 z-slabs via
// incremental plane dots (error ~3e-6 << 1e-4 margin folded into rhs).
// ---------------------------------------------------------------------------
__global__ __launch_bounds__(512) void mask_kernel(
    const float* __restrict__ cul,
    unsigned long long* __restrict__ masks)
{
    const int col = blockIdx.x;           // 0..143 = sx*12+sy
    const int b   = blockIdx.y;
    const int f   = threadIdx.x;          // facet (sorted order)
    const int w   = threadIdx.x >> 6;
    float bminx=CUL(0,b,f), bminy=CUL(1,b,f), bminz=CUL(2,b,f);
    float bmaxx=CUL(3,b,f), bmaxy=CUL(4,b,f), bmaxz=CUL(5,b,f);
    float n0x=CUL(6,b,f),  n0y=CUL(7,b,f),  n0z=CUL(8,b,f),  r0=CUL(9,b,f);
    float n1x=CUL(10,b,f), n1y=CUL(11,b,f), n1z=CUL(12,b,f), r1=CUL(13,b,f);
    float n2x=CUL(14,b,f), n2y=CUL(15,b,f), n2z=CUL(16,b,f), r2=CUL(17,b,f);
    float n3x=CUL(18,b,f), n3y=CUL(19,b,f), n3z=CUL(20,b,f), r3=CUL(21,b,f);

    const int sx = col / 12, sy = col % 12;
    const float cx = (float)(16*sx + 8 - VWD) / 96.0f;
    const float cy = (float)(16*sy + 8 - VWD) / 96.0f;
    const float colminx = (float)(16*sx + 1  - VWD) / 96.0f;
    const float colmaxx = (float)(16*sx + 15 - VWD) / 96.0f;
    const float colminy = (float)(16*sy + 1  - VWD) / 96.0f;
    const float colmaxy = (float)(16*sy + 15 - VWD) / 96.0f;
    const bool ovxy = (bminx <= colmaxx) & (bmaxx >= colminx) &
                      (bminy <= colmaxy) & (bmaxy >= colminy);

    const float cz0   = (float)(4 - VWD) / 96.0f;   // z-center of slab sz=0
    const float stepc = 8.0f / 96.0f;
    float d0 = n0x*cx + n0y*cy + n0z*cz0 - r0;  float s0 = n0z*stepc;
    float d1 = n1x*cx + n1y*cy + n1z*cz0 - r1;  float s1 = n1z*stepc;
    float d2 = n2x*cx + n2y*cy + n2z*cz0 - r2;  float s2 = n2z*stepc;
    float d3 = n3x*cx + n3y*cy + n3z*cz0 - r3;  float s3 = n3z*stepc;
    float zlo = (float)(1 - VWD) / 96.0f;
    float zhi = (float)(7 - VWD) / 96.0f;

    unsigned long long* mp = masks + ((size_t)b * NSLAB + (size_t)col * 24) * 8 + w;
#pragma unroll 4
    for (int sz = 0; sz < 24; ++sz) {
        bool ov = ovxy & (bminz <= zhi) & (bmaxz >= zlo) &
                  (d0 <= 0.0f) & (d1 <= 0.0f) & (d2 <= 0.0f) & (d3 <= 0.0f);
        unsigned long long bal = __ballot((int)ov);
        if ((threadIdx.x & 63) == 0) mp[(size_t)sz * 8] = bal;
        d0 += s0; d1 += s1; d2 += s2; d3 += s3;
        zlo += stepc; zhi += stepc;
    }
}

// ---------------------------------------------------------------------------
// Kernel 3 (R11 math + scalar record loads): 2-WAVE blocks (128 thr) for
// fine-grained residency — up to 16 blocks/CU x 2 waves = full 32 waves/CU,
// and retiring waves free slots at 2x finer grain than 256-thr blocks.
// Per candidate: numerators bit-identical to ref; exact l_i>=0 sign test;
// det-relative shell on the sum; a per-lane 4-bit `need` mask accumulates
// shell hits so only ONE __any branch per candidate guards the (rare, ~2%)
// exact-division path.
// ---------------------------------------------------------------------------
__global__ __launch_bounds__(128) void voxelize_kernel(
    const float*              __restrict__ body,
    const unsigned long long* __restrict__ masks,
    float*                    __restrict__ out)
{
    const int b    = blockIdx.y;
    const int wave = threadIdx.x >> 6;
    const int lane = threadIdx.x & 63;
    const int slab = blockIdx.x * 2 + wave;          // 0 .. 3455
    const int sz = slab % 24;
    const int sy = (slab / 24) % 12;
    const int sx = slab / 288;
    const int ix  = sx*8 + (lane >> 3);
    const int iy  = sy*8 + (lane & 7);
    const int iz0 = sz*4;

    const float px  = (float)(2*ix + 1 - VWD) / 96.0f;
    const float py  = (float)(2*iy + 1 - VWD) / 96.0f;
    const float pz0 = (float)(2*(iz0+0) + 1 - VWD) / 96.0f;
    const float pz1 = (float)(2*(iz0+1) + 1 - VWD) / 96.0f;
    const float pz2 = (float)(2*(iz0+2) + 1 - VWD) / 96.0f;
    const float pz3 = (float)(2*(iz0+3) + 1 - VWD) / 96.0f;

    const unsigned long long* mp = masks + ((size_t)b * NSLAB + slab) * 8;
    const float* bb = body + (size_t)b * NFAC * RECF;

    unsigned fnd = 0u;   // bit k = voxel (ix,iy,iz0+k) found
    for (int w = 0; w < 8; ++w) {
        unsigned long long m = mp[w];   // wave-uniform -> SGPR
        while (m) {
            int bit = __builtin_ctzll(m);
            m &= m - 1;
            int f = __builtin_amdgcn_readfirstlane(w * 64 + bit);
            const float* bo = bb + f * RECF;
            float det = bo[0], v3x = bo[1], v3y = bo[2], v3z = bo[3];
            float A00 = bo[4],  A01 = bo[5],  A02 = bo[6],  A10 = bo[7];
            float A11 = bo[8],  A12 = bo[9],  A20 = bo[10], A21 = bo[11];
            float A22 = bo[12], dhi = bo[13], mhi = bo[14];
            float dx = px - v3x, dy = py - v3y;
            // ref-exact partials (left-assoc, contract off)
            float p0 = A00*dx + A01*dy;
            float p1 = A10*dx + A11*dy;
            float p2 = A20*dx + A21*dy;
            float dzk0 = pz0 - v3z, dzk1 = pz1 - v3z;
            float dzk2 = pz2 - v3z, dzk3 = pz3 - v3z;
            unsigned need = 0u;   // bit k: lane in shell, must run exact path
#pragma unroll
            for (int k = 0; k < 4; ++k) {
                float dzk = (k == 0) ? dzk0 : (k == 1) ? dzk1
                          : (k == 2) ? dzk2 : dzk3;
                // n_i bit-identical to reference's numerators
                float n0 = p0 + A02*dzk;
                float n1 = p1 + A12*dzk;
                float n2 = p2 + A22*dzk;
                float sm = (n0 + n1) + n2;
                float mn = fminf(fminf(n0, n1), n2);   // v_min3_f32
                bool ge0 = (mn >= 0.0f);               // EXACT l_i>=0 test
                bool def = ge0 & (sm <= dhi);
                bool may = ge0 & (sm <= mhi);
                if (may & !def & !((fnd >> k) & 1u)) need |= (1u << k);
                if (def) fnd |= (1u << k);
            }
            if (__any(need != 0u)) {
                // exact path (rare): ref's divisions + final test, per k
#pragma unroll
                for (int k = 0; k < 4; ++k) {
                    float dzk = (k == 0) ? dzk0 : (k == 1) ? dzk1
                              : (k == 2) ? dzk2 : dzk3;
                    float n0 = p0 + A02*dzk;
                    float n1 = p1 + A12*dzk;
                    float n2 = p2 + A22*dzk;
                    float l0 = n0 / det;
                    float l1 = n1 / det;
                    float l2 = n2 / det;
                    float l3 = 1.0f - ((l0 + l1) + l2);
                    bool inside = (l0 >= 0.0f) & (l0 <= 1.0f) &
                                  (l1 >= 0.0f) & (l1 <= 1.0f) &
                                  (l2 >= 0.0f) & (l2 <= 1.0f) &
                                  (l3 >= 0.0f) & (l3 <= 1.0f);
                    if (((need >> k) & 1u) & inside) fnd |= (1u << k);
                }
            }
            if (__all(fnd == 15u)) goto done;
        }
    }
done:
    float4 v;
    v.x = (fnd & 1u) ? 1.0f : 0.0f;
    v.y = (fnd & 2u) ? 1.0f : 0.0f;
    v.z = (fnd & 4u) ? 1.0f : 0.0f;
    v.w = (fnd & 8u) ? 1.0f : 0.0f;
    *(float4*)&out[(size_t)b*(VWD*VWD*VWD) + (size_t)ix*(VWD*VWD) + iy*VWD + iz0] = v;
}

extern "C" void kernel_launch(void* const* d_in, const int* in_sizes, int n_in,
                              void* d_out, int out_size, void* d_ws, size_t ws_size,
                              hipStream_t stream) {
    const float* vertices = (const float*)d_in[0];   // (8, 2048, 3) f32
    const int*   facets   = (const int*)d_in[1];     // (8, 512, 4) int
    float*       out      = (float*)d_out;           // (8, 96, 96, 96) f32

    // d_ws layout: cul SoA (352 KB) | body (256 KB) | masks (1.73 MB)
    float* cul  = (float*)d_ws;
    float* body = (float*)((char*)d_ws + (size_t)CULC * NBATCH * NFAC * 4);
    unsigned long long* msk =
        (unsigned long long*)((char*)d_ws +
                              (size_t)(CULC + RECF) * NBATCH * NFAC * 4);

    precompute_kernel<<<NBATCH, 512, 0, stream>>>(vertices, facets, cul, body);
    mask_kernel<<<dim3(144, NBATCH), 512, 0, stream>>>(cul, msk);
    dim3 grid(NSLAB / 2, NBATCH);   // 1728 blocks x 2 waves = 3456 slabs/batch
    voxelize_kernel<<<grid, 128, 0, stream>>>(body, msk, out);
}